// Round 9
// baseline (1197.835 us; speedup 1.0000x reference)
//
#include <hip/hip_runtime.h>

// ConditionalCNF via MFMA (round 9): Pade[9/8] tanh (removes all v_exp) with
// SESSION-VERIFIED primitives only — division via plain v_rcp_f32 (used in all
// passing rounds), bf16 pack via v_perm round-half-up (r2-r7-verified).
// Round-8's blowup is bracketed to its two unverified primitives (magic-seed
// Newton rcp / cvt_pk_bf16 builtin); both removed.
//   tanh(x) ~= x*N(u)/D(u), u=x^2, x clamped to [-4,4]
//   N = u^3 + 378u^2 + 17325u + 135135
//   D = 28u^3 + 3150u^2 + 62370u + 135135   (max err ~3e-5 on [-4,4];
//   saturation err 6.7e-4 past the clamp — both far under bf16 rounding)
//
// Verified layouts (rounds 2/4/5/6/7 passed):
//   A-frag:  A[m=lane&15][k=(lane>>4)*8+j]
//   B-frag:  B[k=(lane>>4)*8+j][n=lane&15]
//   C/D:     col=lane&15 (unit), row=(lane>>4)*4+reg (sample-within-block)
//   owner lane o: sample 16*((o>>2)&3) + 4*(o>>4) + (o&3)

typedef __attribute__((ext_vector_type(8))) short short8;
typedef __attribute__((ext_vector_type(4))) float floatx4;
typedef __attribute__((ext_vector_type(2))) float float2v;

constexpr int NSTEPS = 20;

struct U128 { unsigned a, b, c, d; };

__device__ __forceinline__ float2v vfma(float2v a, float2v b, float2v c) {
#if __has_builtin(__builtin_elementwise_fma)
    return __builtin_elementwise_fma(a, b, c);
#else
    float2v d; d.x = fmaf(a.x, b.x, c.x); d.y = fmaf(a.y, b.y, c.y); return d;
#endif
}

__device__ __forceinline__ float2v vclamp4(float2v x) {
#if __has_builtin(__builtin_elementwise_max) && __has_builtin(__builtin_elementwise_min)
    return __builtin_elementwise_min(
        __builtin_elementwise_max(x, (float2v){-4.0f, -4.0f}),
        (float2v){4.0f, 4.0f});
#else
    float2v r;
    r.x = fminf(fmaxf(x.x, -4.0f), 4.0f);
    r.y = fminf(fmaxf(x.y, -4.0f), 4.0f);
    return r;
#endif
}

// Pade[9/8] packed tanh; division via v_rcp_f32 (session-verified accuracy).
__device__ __forceinline__ float2v tanh_rat(float2v x) {
    const float2v xc = vclamp4(x);
    const float2v u = xc * xc;
    float2v n = u + (float2v){378.0f, 378.0f};
    n = vfma(n, u, (float2v){17325.0f, 17325.0f});
    n = vfma(n, u, (float2v){135135.0f, 135135.0f});
    float2v d = vfma(u, (float2v){28.0f, 28.0f}, (float2v){3150.0f, 3150.0f});
    d = vfma(d, u, (float2v){62370.0f, 62370.0f});
    d = vfma(d, u, (float2v){135135.0f, 135135.0f});
    const float2v p = {__builtin_amdgcn_rcpf(d.x), __builtin_amdgcn_rcpf(d.y)};
    return (xc * n) * p;
}

// pack two f32 -> bf16x2, round-half-up (+0x8000, high halves via v_perm) —
// the r2-r7-verified pack.  lo16 = bf16(a), hi16 = bf16(b).
__device__ __forceinline__ unsigned pack2bf(float a, float b) {
    unsigned ua = __builtin_bit_cast(unsigned, a) + 0x8000u;
    unsigned ub = __builtin_bit_cast(unsigned, b) + 0x8000u;
    return __builtin_amdgcn_perm(ub, ua, 0x07060302u);
}
__device__ __forceinline__ float bf2f(unsigned bf) {
    return __builtin_bit_cast(float, bf << 16);
}

template <int CTRL>
__device__ __forceinline__ float dpp_radd(float x) {
    int y = __builtin_amdgcn_update_dpp(0, __builtin_bit_cast(int, x), CTRL, 0xf, 0xf, true);
    return x + __builtin_bit_cast(float, y);
}
template <int PAT>
__device__ __forceinline__ float swz_add(float x) {
    int y = __builtin_amdgcn_ds_swizzle(__builtin_bit_cast(int, x), PAT);
    return x + __builtin_bit_cast(float, y);
}

// Sum 4 independent values across each 16-lane row; lane ends holding the full
// row-sum of value index (lane&3).  mo=(lane&1), mt=(lane&2).
__device__ __forceinline__ float reduce4(float v0, float v1, float v2, float v3,
                                         bool mo, bool mt) {
    v0 = dpp_radd<0xB1>(v0);            // + xor1
    v1 = dpp_radd<0xB1>(v1);
    v2 = dpp_radd<0xB1>(v2);
    v3 = dpp_radd<0xB1>(v3);
    float a01 = mo ? v1 : v0;
    float a23 = mo ? v3 : v2;
    a01 = dpp_radd<0x4E>(a01);          // + xor2
    a23 = dpp_radd<0x4E>(a23);
    float a = mt ? a23 : a01;
    a = swz_add<0x101F>(a);             // + xor4
    a = swz_add<0x201F>(a);             // + xor8
    return a;
}

__global__ __launch_bounds__(256) void cnf_mfma(
    const float* __restrict__ Tin, const float* __restrict__ cond,
    const float* __restrict__ W1, const float* __restrict__ b1,
    const float* __restrict__ W2, const float* __restrict__ b2,
    const float* __restrict__ W3, const float* __restrict__ b3,
    float* __restrict__ out, int B)
{
    const int tid   = threadIdx.x;
    const int lane  = tid & 63;
    const int wbase = blockIdx.x * 256 + (tid >> 6) * 64;

    const int m   = lane & 15;
    const int qk  = lane >> 4;
    const int b_o = (lane >> 2) & 3;
    const int r_o = lane & 3;
    const int s_own = 16 * b_o + 4 * qk + r_o;

    const bool mo = (lane & 1) != 0;
    const bool mt = (lane & 2) != 0;
    bool bsel[4];
#pragma unroll
    for (int b = 0; b < 4; ++b) bsel[b] = (b_o == b);

    // bpermute byte-address base; block b's address = addr0 + 16*b
    const int addr0 = ((m >> 2) * 16 + (m & 3)) * 4;

    // ---- B fragments: W2 hi/lo bf16 split; per-lane column constants ----
    short8 Bhi[2], Blo[2];
    float2v w3pv[2], cb2p[2];
#pragma unroll
    for (int t = 0; t < 2; ++t) {
        const int u = m + 16 * t;
        const float* w2r = W2 + u * 32 + qk * 8;
        unsigned hu[4], lu[4];
#pragma unroll
        for (int p = 0; p < 4; ++p) {
            const float w0 = w2r[2 * p], w1v = w2r[2 * p + 1];
            const unsigned h0 = (__builtin_bit_cast(unsigned, w0) + 0x8000u) >> 16;
            const unsigned h1 = (__builtin_bit_cast(unsigned, w1v) + 0x8000u) >> 16;
            hu[p] = h0 | (h1 << 16);
            lu[p] = pack2bf(w0 - bf2f(h0), w1v - bf2f(h1));
        }
        Bhi[t] = __builtin_bit_cast(short8, U128{hu[0], hu[1], hu[2], hu[3]});
        Blo[t] = __builtin_bit_cast(short8, U128{lu[0], lu[1], lu[2], lu[3]});
        const float w3v = W3[u];
        w3pv[t] = float2v{w3v, w3v};
        const float cv = b2[u];
        cb2p[t] = float2v{cv, cv};
    }

    // ---- layer-1 constants for this lane's k-chunk (raw weights) ----
    float2v w1z2[4];
#pragma unroll
    for (int p = 0; p < 4; ++p)
        w1z2[p] = float2v{W1[(qk * 8 + 2 * p) * 9], W1[(qk * 8 + 2 * p + 1) * 9]};

    float2v c12[4][4];
#pragma unroll
    for (int b = 0; b < 4; ++b) {
        int s = wbase + 16 * b + m;
        if (s > B - 1) s = B - 1;
        const float4* c4 = reinterpret_cast<const float4*>(cond + (size_t)s * 8);
        const float4 ca = c4[0], cb = c4[1];
        const float cd[8] = {ca.x, ca.y, ca.z, ca.w, cb.x, cb.y, cb.z, cb.w};
        float c1[8];
#pragma unroll
        for (int j = 0; j < 8; ++j) {
            const int k = qk * 8 + j;
            float acc = b1[k];
#pragma unroll
            for (int jj = 0; jj < 8; ++jj) acc = fmaf(cd[jj], W1[k * 9 + 1 + jj], acc);
            c1[j] = acc;
        }
#pragma unroll
        for (int p = 0; p < 4; ++p) c12[b][p] = float2v{c1[2 * p], c1[2 * p + 1]};
    }

    const floatx4 zero = {0.0f, 0.0f, 0.0f, 0.0f};

    const float b3v = b3[0];
    const int sg = wbase + s_own;
    float z = Tin[sg < B ? sg : B - 1];
    float dlog = 0.0f;
    const float dt = 1.0f / (float)NSTEPS;

    for (int step = 0; step < NSTEPS; ++step) {
        float kz = 0.0f, accz = 0.0f, accl = 0.0f;
#pragma unroll 1
        for (int s4 = 0; s4 < 4; ++s4) {
            const float a = (s4 == 0) ? 0.0f : ((s4 == 3) ? dt : 0.5f * dt);
            const float w = ((s4 == 0) | (s4 == 3)) ? (dt * (1.0f / 6.0f))
                                                    : (dt * (1.0f / 3.0f));
            const int zi = __builtin_bit_cast(int, fmaf(a, kz, z));
            float selx = 0.0f, sely = 0.0f;

#pragma unroll
            for (int b = 0; b < 4; ++b) {
                const float zin = __builtin_bit_cast(
                    float, __builtin_amdgcn_ds_bpermute(addr0 + 16 * b, zi));
                const float2v zz = {zin, zin};

                // ---- A-prep: h1 (bf16) and d1 (bf16), both rounded ----
                unsigned ahp[4], adp[4];
#pragma unroll
                for (int p = 0; p < 4; ++p) {
                    const float2v xs = vfma(zz, w1z2[p], c12[b][p]);  // preact1
                    const float2v h  = tanh_rat(xs);
                    ahp[p] = pack2bf(h.x, h.y);
                    const float2v u  = h * h;
                    const float2v d  = vfma(u, -w1z2[p], w1z2[p]);    // (1-h^2)*w1z
                    adp[p] = pack2bf(d.x, d.y);
                }
                const short8 Ah = __builtin_bit_cast(short8, U128{ahp[0], ahp[1], ahp[2], ahp[3]});
                const short8 Ad = __builtin_bit_cast(short8, U128{adp[0], adp[1], adp[2], adp[3]});

                floatx4 Dh0 = __builtin_amdgcn_mfma_f32_16x16x32_bf16(Ah, Blo[0], zero, 0, 0, 0);
                Dh0         = __builtin_amdgcn_mfma_f32_16x16x32_bf16(Ah, Bhi[0], Dh0,  0, 0, 0);
                floatx4 Dh1 = __builtin_amdgcn_mfma_f32_16x16x32_bf16(Ah, Blo[1], zero, 0, 0, 0);
                Dh1         = __builtin_amdgcn_mfma_f32_16x16x32_bf16(Ah, Bhi[1], Dh1,  0, 0, 0);
                floatx4 Dd0 = __builtin_amdgcn_mfma_f32_16x16x32_bf16(Ad, Blo[0], zero, 0, 0, 0);
                Dd0         = __builtin_amdgcn_mfma_f32_16x16x32_bf16(Ad, Bhi[0], Dd0,  0, 0, 0);
                floatx4 Dd1 = __builtin_amdgcn_mfma_f32_16x16x32_bf16(Ad, Blo[1], zero, 0, 0, 0);
                Dd1         = __builtin_amdgcn_mfma_f32_16x16x32_bf16(Ad, Bhi[1], Dd1,  0, 0, 0);

                // ---- D-processing, packed over adjacent accumulator rows ----
                const float2v Dh0lo = __builtin_shufflevector(Dh0, Dh0, 0, 1);
                const float2v Dh0hi = __builtin_shufflevector(Dh0, Dh0, 2, 3);
                const float2v Dh1lo = __builtin_shufflevector(Dh1, Dh1, 0, 1);
                const float2v Dh1hi = __builtin_shufflevector(Dh1, Dh1, 2, 3);
                const float2v Dd0lo = __builtin_shufflevector(Dd0, Dd0, 0, 1);
                const float2v Dd0hi = __builtin_shufflevector(Dd0, Dd0, 2, 3);
                const float2v Dd1lo = __builtin_shufflevector(Dd1, Dd1, 0, 1);
                const float2v Dd1hi = __builtin_shufflevector(Dd1, Dd1, 2, 3);

                const float2v h2a_lo = tanh_rat(Dh0lo + cb2p[0]);
                const float2v h2a_hi = tanh_rat(Dh0hi + cb2p[0]);
                const float2v h2b_lo = tanh_rat(Dh1lo + cb2p[1]);
                const float2v h2b_hi = tanh_rat(Dh1hi + cb2p[1]);

                const float2v va_lo = vfma(h2b_lo, w3pv[1], h2a_lo * w3pv[0]);
                const float2v va_hi = vfma(h2b_hi, w3pv[1], h2a_hi * w3pv[0]);

                const float2v ta_lo = Dd0lo * w3pv[0];
                const float2v ta_hi = Dd0hi * w3pv[0];
                const float2v tb_lo = Dd1lo * w3pv[1];
                const float2v tb_hi = Dd1hi * w3pv[1];
                const float2v vd_lo = vfma(h2a_lo * h2a_lo, -ta_lo, ta_lo)
                                    + vfma(h2b_lo * h2b_lo, -tb_lo, tb_lo);
                const float2v vd_hi = vfma(h2a_hi * h2a_hi, -ta_hi, ta_hi)
                                    + vfma(h2b_hi * h2b_hi, -tb_hi, tb_hi);

                // ---- merged reduction; result indexed by lane&3 == r_o ----
                const float fz = reduce4(va_lo.x, va_lo.y, va_hi.x, va_hi.y, mo, mt);
                const float fl = reduce4(vd_lo.x, vd_lo.y, vd_hi.x, vd_hi.y, mo, mt);
                selx = bsel[b] ? fz : selx;
                sely = bsel[b] ? fl : sely;
            }
            kz = selx + b3v;
            accz = fmaf(w, kz, accz);
            accl = fmaf(w, sely, accl);
        }
        z += accz;
        dlog += accl;
    }

    if (sg < B) {
        out[sg] = z;
        out[(size_t)B + sg] = dlog;
    }
}

extern "C" void kernel_launch(void* const* d_in, const int* in_sizes, int n_in,
                              void* d_out, int out_size, void* d_ws, size_t ws_size,
                              hipStream_t stream) {
    const float* T    = (const float*)d_in[0];
    const float* cond = (const float*)d_in[1];
    const float* W1   = (const float*)d_in[2];
    const float* b1   = (const float*)d_in[3];
    const float* W2   = (const float*)d_in[4];
    const float* b2   = (const float*)d_in[5];
    const float* W3   = (const float*)d_in[6];
    const float* b3   = (const float*)d_in[7];
    float* out = (float*)d_out;

    const int B = in_sizes[0];
    const int grid = (B + 255) / 256;
    cnf_mfma<<<grid, 256, 0, stream>>>(T, cond, W1, b1, W2, b2, W3, b3, out, B);
}

// Round 10
// 993.905 us; speedup vs baseline: 1.2052x; 1.2052x over previous
//
#include <hip/hip_runtime.h>

// ConditionalCNF via MFMA (round 10): exact r7 baseline (1007us, absmax
// 0.0156) with ONE change — the reduction's ds_swizzle xor4/xor8 stages are
// replaced by DPP row_ror:4/row_ror:8 adds.  For a 4-quad SUM, rotation is
// equivalent to xor pairing (same association, bitwise-identical result), and
// it moves 16 DS-pipe ops/eval (~30cyc latency, 9-deep dep chains) onto the
// VALU pipe.  r9 lesson: exp2-tanh is optimal (trans ~8cyc, pk ~4cyc; Pade
// rational regressed 19%) — r7's scale-folded tanh retained.
//
// Verified layouts (rounds 2/4/5/6/7 passed):
//   A-frag:  A[m=lane&15][k=(lane>>4)*8+j]
//   B-frag:  B[k=(lane>>4)*8+j][n=lane&15]
//   C/D:     col=lane&15 (unit), row=(lane>>4)*4+reg (sample-within-block)
//   owner lane o: sample 16*((o>>2)&3) + 4*(o>>4) + (o&3)
//
// Scaling (s = 2*log2 e): W1z, c1, W2, b2 pre-scaled by s so every tanh is
// exp2 -> +1 -> rcp -> fma.  d-path carries s^2, compensated via w3/s^2.

typedef __attribute__((ext_vector_type(8))) short short8;
typedef __attribute__((ext_vector_type(4))) float floatx4;
typedef __attribute__((ext_vector_type(2))) float float2v;

constexpr int NSTEPS = 20;
constexpr float SCL = 2.8853900817779268f;   // 2*log2(e)

struct U128 { unsigned a, b, c, d; };

__device__ __forceinline__ float fexp2(float x) {
#if __has_builtin(__builtin_amdgcn_exp2f)
    return __builtin_amdgcn_exp2f(x);
#else
    return exp2f(x);
#endif
}

__device__ __forceinline__ float2v vfma(float2v a, float2v b, float2v c) {
#if __has_builtin(__builtin_elementwise_fma)
    return __builtin_elementwise_fma(a, b, c);
#else
    float2v d; d.x = fmaf(a.x, b.x, c.x); d.y = fmaf(a.y, b.y, c.y); return d;
#endif
}

// packed tanh with pre-scaled inputs xs = 2*log2(e)*x: tanh = 1 - 2/(exp2+1)
__device__ __forceinline__ float2v tanh_pk(float2v xs) {
    float2v e = {fexp2(xs.x), fexp2(xs.y)};
    float2v ep = e + float2v{1.0f, 1.0f};
    float2v r = {__builtin_amdgcn_rcpf(ep.x), __builtin_amdgcn_rcpf(ep.y)};
    return vfma(r, float2v{-2.0f, -2.0f}, float2v{1.0f, 1.0f});
}

// pack two f32 -> bf16x2, round-half-up (+0x8000, high halves via v_perm)
__device__ __forceinline__ unsigned pack2bf(float a, float b) {
    unsigned ua = __builtin_bit_cast(unsigned, a) + 0x8000u;
    unsigned ub = __builtin_bit_cast(unsigned, b) + 0x8000u;
    return __builtin_amdgcn_perm(ub, ua, 0x07060302u);   // lo16=bf16(a), hi16=bf16(b)
}
__device__ __forceinline__ float bf2f(unsigned bf) {
    return __builtin_bit_cast(float, bf << 16);
}

template <int CTRL>
__device__ __forceinline__ float dpp_radd(float x) {
    int y = __builtin_amdgcn_update_dpp(0, __builtin_bit_cast(int, x), CTRL, 0xf, 0xf, true);
    return x + __builtin_bit_cast(float, y);
}

// Sum 4 independent values across each 16-lane row; lane ends holding the full
// row-sum of value index (lane&3).  mo=(lane&1), mt=(lane&2).
// Stages: xor1 (quad_perm), merge, xor2 (quad_perm), merge, then the 4
// quad-partials are combined by row_ror:4 + row_ror:8 — pure-DPP, no DS pipe.
// Association (q0+q1)+(q2+q3) is identical to the xor4/xor8 version.
__device__ __forceinline__ float reduce4(float v0, float v1, float v2, float v3,
                                         bool mo, bool mt) {
    v0 = dpp_radd<0xB1>(v0);            // + xor1 (quad_perm [1,0,3,2])
    v1 = dpp_radd<0xB1>(v1);
    v2 = dpp_radd<0xB1>(v2);
    v3 = dpp_radd<0xB1>(v3);
    float a01 = mo ? v1 : v0;
    float a23 = mo ? v3 : v2;
    a01 = dpp_radd<0x4E>(a01);          // + xor2 (quad_perm [2,3,0,1])
    a23 = dpp_radd<0x4E>(a23);
    float a = mt ? a23 : a01;
    a = dpp_radd<0x124>(a);             // + row_ror:4  (quad q += q+1)
    a = dpp_radd<0x128>(a);             // + row_ror:8  (+= opposite pair)
    return a;
}

__global__ __launch_bounds__(256) void cnf_mfma(
    const float* __restrict__ Tin, const float* __restrict__ cond,
    const float* __restrict__ W1, const float* __restrict__ b1,
    const float* __restrict__ W2, const float* __restrict__ b2,
    const float* __restrict__ W3, const float* __restrict__ b3,
    float* __restrict__ out, int B)
{
    const int tid   = threadIdx.x;
    const int lane  = tid & 63;
    const int wbase = blockIdx.x * 256 + (tid >> 6) * 64;

    const int m   = lane & 15;
    const int qk  = lane >> 4;
    const int b_o = (lane >> 2) & 3;
    const int r_o = lane & 3;
    const int s_own = 16 * b_o + 4 * qk + r_o;

    const bool mo = (lane & 1) != 0;
    const bool mt = (lane & 2) != 0;
    bool bsel[4];
#pragma unroll
    for (int b = 0; b < 4; ++b) bsel[b] = (b_o == b);

    // bpermute byte-address base; block b's address = addr0 + 16*b
    const int addr0 = ((m >> 2) * 16 + (m & 3)) * 4;

    // ---- B fragments: s*W2, hi/lo bf16 split; per-lane column constants ----
    short8 Bhi[2], Blo[2];
    float2v w3pv[2], w3qv[2], cb2p[2];
    const float is2 = 1.0f / (SCL * SCL);
#pragma unroll
    for (int t = 0; t < 2; ++t) {
        const int u = m + 16 * t;
        const float* w2r = W2 + u * 32 + qk * 8;
        unsigned hu[4], lu[4];
#pragma unroll
        for (int p = 0; p < 4; ++p) {
            const float w0 = SCL * w2r[2 * p], w1v = SCL * w2r[2 * p + 1];
            const unsigned h0 = (__builtin_bit_cast(unsigned, w0) + 0x8000u) >> 16;
            const unsigned h1 = (__builtin_bit_cast(unsigned, w1v) + 0x8000u) >> 16;
            hu[p] = h0 | (h1 << 16);
            lu[p] = pack2bf(w0 - bf2f(h0), w1v - bf2f(h1));
        }
        Bhi[t] = __builtin_bit_cast(short8, U128{hu[0], hu[1], hu[2], hu[3]});
        Blo[t] = __builtin_bit_cast(short8, U128{lu[0], lu[1], lu[2], lu[3]});
        const float w3v = W3[u];
        w3pv[t] = float2v{w3v, w3v};
        w3qv[t] = float2v{w3v * is2, w3v * is2};
        const float cv = SCL * b2[u];
        cb2p[t] = float2v{cv, cv};
    }

    // ---- layer-1 constants for this lane's k-chunk (pre-scaled by s) ----
    float2v w1z2[4];
#pragma unroll
    for (int p = 0; p < 4; ++p)
        w1z2[p] = float2v{SCL * W1[(qk * 8 + 2 * p) * 9],
                          SCL * W1[(qk * 8 + 2 * p + 1) * 9]};

    float2v c12[4][4];
#pragma unroll
    for (int b = 0; b < 4; ++b) {
        int s = wbase + 16 * b + m;
        if (s > B - 1) s = B - 1;
        const float4* c4 = reinterpret_cast<const float4*>(cond + (size_t)s * 8);
        const float4 ca = c4[0], cb = c4[1];
        const float cd[8] = {ca.x, ca.y, ca.z, ca.w, cb.x, cb.y, cb.z, cb.w};
        float c1[8];
#pragma unroll
        for (int j = 0; j < 8; ++j) {
            const int k = qk * 8 + j;
            float acc = b1[k];
#pragma unroll
            for (int jj = 0; jj < 8; ++jj) acc = fmaf(cd[jj], W1[k * 9 + 1 + jj], acc);
            c1[j] = SCL * acc;
        }
#pragma unroll
        for (int p = 0; p < 4; ++p) c12[b][p] = float2v{c1[2 * p], c1[2 * p + 1]};
    }

    const floatx4 zero = {0.0f, 0.0f, 0.0f, 0.0f};

    const float b3v = b3[0];
    const int sg = wbase + s_own;
    float z = Tin[sg < B ? sg : B - 1];
    float dlog = 0.0f;
    const float dt = 1.0f / (float)NSTEPS;

    for (int step = 0; step < NSTEPS; ++step) {
        float kz = 0.0f, accz = 0.0f, accl = 0.0f;
#pragma unroll 1
        for (int s4 = 0; s4 < 4; ++s4) {
            const float a = (s4 == 0) ? 0.0f : ((s4 == 3) ? dt : 0.5f * dt);
            const float w = ((s4 == 0) | (s4 == 3)) ? (dt * (1.0f / 6.0f))
                                                    : (dt * (1.0f / 3.0f));
            const int zi = __builtin_bit_cast(int, fmaf(a, kz, z));
            float selx = 0.0f, sely = 0.0f;

#pragma unroll
            for (int b = 0; b < 4; ++b) {
                const float zin = __builtin_bit_cast(
                    float, __builtin_amdgcn_ds_bpermute(addr0 + 16 * b, zi));
                const float2v zz = {zin, zin};

                // ---- A-prep: h1 (bf16) and s*d1 (bf16), both rounded ----
                unsigned ahp[4], adp[4];
#pragma unroll
                for (int p = 0; p < 4; ++p) {
                    const float2v xs = vfma(zz, w1z2[p], c12[b][p]);  // s*preact1
                    const float2v h  = tanh_pk(xs);
                    ahp[p] = pack2bf(h.x, h.y);
                    const float2v u  = h * h;
                    const float2v d  = vfma(u, -w1z2[p], w1z2[p]);    // (1-h^2)*s*w1z
                    adp[p] = pack2bf(d.x, d.y);
                }
                const short8 Ah = __builtin_bit_cast(short8, U128{ahp[0], ahp[1], ahp[2], ahp[3]});
                const short8 Ad = __builtin_bit_cast(short8, U128{adp[0], adp[1], adp[2], adp[3]});

                floatx4 Dh0 = __builtin_amdgcn_mfma_f32_16x16x32_bf16(Ah, Blo[0], zero, 0, 0, 0);
                Dh0         = __builtin_amdgcn_mfma_f32_16x16x32_bf16(Ah, Bhi[0], Dh0,  0, 0, 0);
                floatx4 Dh1 = __builtin_amdgcn_mfma_f32_16x16x32_bf16(Ah, Blo[1], zero, 0, 0, 0);
                Dh1         = __builtin_amdgcn_mfma_f32_16x16x32_bf16(Ah, Bhi[1], Dh1,  0, 0, 0);
                floatx4 Dd0 = __builtin_amdgcn_mfma_f32_16x16x32_bf16(Ad, Blo[0], zero, 0, 0, 0);
                Dd0         = __builtin_amdgcn_mfma_f32_16x16x32_bf16(Ad, Bhi[0], Dd0,  0, 0, 0);
                floatx4 Dd1 = __builtin_amdgcn_mfma_f32_16x16x32_bf16(Ad, Blo[1], zero, 0, 0, 0);
                Dd1         = __builtin_amdgcn_mfma_f32_16x16x32_bf16(Ad, Bhi[1], Dd1,  0, 0, 0);

                // ---- D-processing, packed over adjacent accumulator rows ----
                const float2v Dh0lo = __builtin_shufflevector(Dh0, Dh0, 0, 1);
                const float2v Dh0hi = __builtin_shufflevector(Dh0, Dh0, 2, 3);
                const float2v Dh1lo = __builtin_shufflevector(Dh1, Dh1, 0, 1);
                const float2v Dh1hi = __builtin_shufflevector(Dh1, Dh1, 2, 3);
                const float2v Dd0lo = __builtin_shufflevector(Dd0, Dd0, 0, 1);
                const float2v Dd0hi = __builtin_shufflevector(Dd0, Dd0, 2, 3);
                const float2v Dd1lo = __builtin_shufflevector(Dd1, Dd1, 0, 1);
                const float2v Dd1hi = __builtin_shufflevector(Dd1, Dd1, 2, 3);

                // bias added here (cb2p), layer-2 tanh
                const float2v h2a_lo = tanh_pk(Dh0lo + cb2p[0]);
                const float2v h2a_hi = tanh_pk(Dh0hi + cb2p[0]);
                const float2v h2b_lo = tanh_pk(Dh1lo + cb2p[1]);
                const float2v h2b_hi = tanh_pk(Dh1hi + cb2p[1]);

                const float2v va_lo = vfma(h2b_lo, w3pv[1], h2a_lo * w3pv[0]);
                const float2v va_hi = vfma(h2b_hi, w3pv[1], h2a_hi * w3pv[0]);

                const float2v ta_lo = Dd0lo * w3qv[0];
                const float2v ta_hi = Dd0hi * w3qv[0];
                const float2v tb_lo = Dd1lo * w3qv[1];
                const float2v tb_hi = Dd1hi * w3qv[1];
                const float2v vd_lo = vfma(h2a_lo * h2a_lo, -ta_lo, ta_lo)
                                    + vfma(h2b_lo * h2b_lo, -tb_lo, tb_lo);
                const float2v vd_hi = vfma(h2a_hi * h2a_hi, -ta_hi, ta_hi)
                                    + vfma(h2b_hi * h2b_hi, -tb_hi, tb_hi);

                // ---- merged all-DPP reduction; result indexed by lane&3 ----
                const float fz = reduce4(va_lo.x, va_lo.y, va_hi.x, va_hi.y, mo, mt);
                const float fl = reduce4(vd_lo.x, vd_lo.y, vd_hi.x, vd_hi.y, mo, mt);
                selx = bsel[b] ? fz : selx;
                sely = bsel[b] ? fl : sely;
            }
            kz = selx + b3v;
            accz = fmaf(w, kz, accz);
            accl = fmaf(w, sely, accl);
        }
        z += accz;
        dlog += accl;
    }

    if (sg < B) {
        out[sg] = z;
        out[(size_t)B + sg] = dlog;
    }
}

extern "C" void kernel_launch(void* const* d_in, const int* in_sizes, int n_in,
                              void* d_out, int out_size, void* d_ws, size_t ws_size,
                              hipStream_t stream) {
    const float* T    = (const float*)d_in[0];
    const float* cond = (const float*)d_in[1];
    const float* W1   = (const float*)d_in[2];
    const float* b1   = (const float*)d_in[3];
    const float* W2   = (const float*)d_in[4];
    const float* b2   = (const float*)d_in[5];
    const float* W3   = (const float*)d_in[6];
    const float* b3   = (const float*)d_in[7];
    float* out = (float*)d_out;

    const int B = in_sizes[0];
    const int grid = (B + 255) / 256;
    cnf_mfma<<<grid, 256, 0, stream>>>(T, cond, W1, b1, W2, b2, W3, b3, out, B);
}